// Round 1
// baseline (3357.429 us; speedup 1.0000x reference)
//
#include <hip/hip_runtime.h>

#define N_NODES 100000
#define N_EDGES 800000
#define N_LABEL 400000
// IN_CH = 256, OUT_CH = 256, H1 = 128, H2 = 32

// ---------------- degree / normalization ----------------
__global__ void k_deg_init(float* __restrict__ deg) {
    int i = blockIdx.x * 256 + threadIdx.x;
    if (i < N_NODES) deg[i] = 1.0f;  // self-loop contributes 1
}

__global__ void k_deg_acc(const int* __restrict__ ei, float* __restrict__ deg) {
    int e = blockIdx.x * 256 + threadIdx.x;
    if (e < N_EDGES) atomicAdd(&deg[ei[N_EDGES + e]], 1.0f);  // dst = ei[1][e]
}

__global__ void k_dis(float* __restrict__ deg) {
    int i = blockIdx.x * 256 + threadIdx.x;
    if (i < N_NODES) deg[i] = rsqrtf(deg[i]);  // deg >= 1 always (self loops)
}

// ---------------- fp32 tiled GEMM: C[M,N] = A[M,K] @ B[K,N] ----------------
// BM=BN=128, BK=16, 256 threads, 8x8 per thread. N % 128 == 0, K % 16 == 0.
__global__ __launch_bounds__(256) void gemm_f32(
    const float* __restrict__ A, const float* __restrict__ B,
    float* __restrict__ C, int M, int N, int K) {
    __shared__ float As[16][132];  // transposed: As[k][m], +4 pad
    __shared__ float Bs[16][132];  // Bs[k][n]

    const int tid = threadIdx.x;
    const int tx = tid & 15, ty = tid >> 4;
    const int m0 = blockIdx.x * 128, n0 = blockIdx.y * 128;

    const int ar = tid >> 2;        // 0..63 (A row within tile, +64 for 2nd half)
    const int ac = (tid & 3) * 4;   // 0,4,8,12 (A col within tile)
    const int bk = tid >> 5;        // 0..7  (B row within tile, +8 for 2nd half)
    const int bc = (tid & 31) * 4;  // 0..124 (B col within tile)

    float acc[8][8] = {};

    for (int k0 = 0; k0 < K; k0 += 16) {
        // load A tile (transposed into LDS), guard rows
        #pragma unroll
        for (int hh = 0; hh < 2; ++hh) {
            int row = m0 + ar + hh * 64;
            float4 v = {0.f, 0.f, 0.f, 0.f};
            if (row < M) v = *(const float4*)&A[(size_t)row * K + k0 + ac];
            As[ac + 0][ar + hh * 64] = v.x;
            As[ac + 1][ar + hh * 64] = v.y;
            As[ac + 2][ar + hh * 64] = v.z;
            As[ac + 3][ar + hh * 64] = v.w;
        }
        // load B tile
        #pragma unroll
        for (int hh = 0; hh < 2; ++hh) {
            int krow = k0 + bk + hh * 8;
            float4 v = *(const float4*)&B[(size_t)krow * N + n0 + bc];
            *(float4*)&Bs[bk + hh * 8][bc] = v;
        }
        __syncthreads();

        #pragma unroll
        for (int kk = 0; kk < 16; ++kk) {
            const float4 a0 = *(const float4*)&As[kk][ty * 8];
            const float4 a1 = *(const float4*)&As[kk][ty * 8 + 4];
            const float4 b0 = *(const float4*)&Bs[kk][tx * 8];
            const float4 b1 = *(const float4*)&Bs[kk][tx * 8 + 4];
            const float aa[8] = {a0.x, a0.y, a0.z, a0.w, a1.x, a1.y, a1.z, a1.w};
            const float bb[8] = {b0.x, b0.y, b0.z, b0.w, b1.x, b1.y, b1.z, b1.w};
            #pragma unroll
            for (int i = 0; i < 8; ++i)
                #pragma unroll
                for (int j = 0; j < 8; ++j)
                    acc[i][j] = fmaf(aa[i], bb[j], acc[i][j]);
        }
        __syncthreads();
    }

    #pragma unroll
    for (int i = 0; i < 8; ++i) {
        int row = m0 + ty * 8 + i;
        if (row < M) {
            float4 c0 = {acc[i][0], acc[i][1], acc[i][2], acc[i][3]};
            float4 c1 = {acc[i][4], acc[i][5], acc[i][6], acc[i][7]};
            *(float4*)&C[(size_t)row * N + n0 + tx * 8] = c0;
            *(float4*)&C[(size_t)row * N + n0 + tx * 8 + 4] = c1;
        }
    }
}

// ---------------- h init: h = b_gcn + dis^2 * hlin (self loop) ----------------
__global__ void k_hinit(const float* __restrict__ hlin, const float* __restrict__ dis,
                        const float* __restrict__ bgcn, float* __restrict__ h) {
    int i = blockIdx.x * 256 + threadIdx.x;  // over N_NODES*64 float4s
    if (i >= N_NODES * 64) return;
    int node = i >> 6;
    int c4 = i & 63;
    float d = dis[node];
    float s = d * d;
    float4 v = ((const float4*)hlin)[i];
    float4 b = ((const float4*)bgcn)[c4];
    float4 r = {b.x + v.x * s, b.y + v.y * s, b.z + v.z * s, b.w + v.w * s};
    ((float4*)h)[i] = r;
}

// ---------------- scatter: h[dst] += hlin[src] * dis[src]*dis[dst] ----------------
__global__ void k_scatter(const float* __restrict__ hlin, const int* __restrict__ ei,
                          const float* __restrict__ dis, float* __restrict__ h) {
    int w = blockIdx.x * 4 + (threadIdx.x >> 6);  // global wave id = edge id
    int lane = threadIdx.x & 63;
    if (w >= N_EDGES) return;
    int src = ei[w];
    int dst = ei[N_EDGES + w];
    float norm = dis[src] * dis[dst];
    float4 v = *(const float4*)&hlin[(size_t)src * 256 + lane * 4];
    float* hp = &h[(size_t)dst * 256 + lane * 4];
    atomicAdd(hp + 0, v.x * norm);
    atomicAdd(hp + 1, v.y * norm);
    atomicAdd(hp + 2, v.z * norm);
    atomicAdd(hp + 3, v.w * norm);
}

// ---------------- fused edge MLP ----------------
// per label edge e: t = relu(g[dst]-g[src]+b1) [128]; u = relu(t@W2+b2) [32];
// out[e] = u . W3 + b3. One wave per edge, 4 edges per block.
__global__ __launch_bounds__(256) void k_edge_mlp(
    const float* __restrict__ g, const int* __restrict__ eli,
    const float* __restrict__ b1, const float* __restrict__ W2,
    const float* __restrict__ b2, const float* __restrict__ W3,
    const float* __restrict__ b3, float* __restrict__ out) {
    __shared__ float sW2[128 * 32];
    __shared__ float st[4][128];

    const int tid = threadIdx.x;
    // stage W2 into LDS
    #pragma unroll
    for (int i = tid * 4; i < 4096; i += 1024)
        *(float4*)&sW2[i] = *(const float4*)&W2[i];

    const int wave = tid >> 6, lane = tid & 63;
    const int e = blockIdx.x * 4 + wave;
    const int src = eli[e];
    const int dst = eli[N_LABEL + e];

    float gd0 = g[(size_t)dst * 128 + lane];
    float gd1 = g[(size_t)dst * 128 + 64 + lane];
    float gs0 = g[(size_t)src * 128 + lane];
    float gs1 = g[(size_t)src * 128 + 64 + lane];
    float t0 = fmaxf(gd0 - gs0 + b1[lane], 0.f);
    float t1 = fmaxf(gd1 - gs1 + b1[64 + lane], 0.f);
    st[wave][lane] = t0;
    st[wave][64 + lane] = t1;
    __syncthreads();

    float r = 0.f;
    if (lane < 32) {
        float acc = b2[lane];
        #pragma unroll 4
        for (int k = 0; k < 128; ++k)
            acc = fmaf(st[wave][k], sW2[k * 32 + lane], acc);
        r = fmaxf(acc, 0.f) * W3[lane];
        #pragma unroll
        for (int m = 16; m; m >>= 1) r += __shfl_xor(r, m);
        if (lane == 0) out[e] = r + b3[0];
    }
}

// ---------------- launch ----------------
extern "C" void kernel_launch(void* const* d_in, const int* in_sizes, int n_in,
                              void* d_out, int out_size, void* d_ws, size_t ws_size,
                              hipStream_t stream) {
    const float* x   = (const float*)d_in[0];
    const int*   ei  = (const int*)d_in[1];
    const int*   eli = (const int*)d_in[2];
    const float* Wg  = (const float*)d_in[3];
    const float* bg  = (const float*)d_in[4];
    const float* W1  = (const float*)d_in[5];
    const float* b1  = (const float*)d_in[6];
    const float* W2  = (const float*)d_in[7];
    const float* b2  = (const float*)d_in[8];
    const float* W3  = (const float*)d_in[9];
    const float* b3  = (const float*)d_in[10];
    float* out = (float*)d_out;

    char* ws = (char*)d_ws;
    float* deg  = (float*)ws;                                   // 400 KB
    float* hlin = (float*)(ws + (1 << 19));                     // 102.4 MB (reused as g)
    float* h    = (float*)(ws + (1 << 19) + 102400000);         // 102.4 MB

    k_deg_init<<<(N_NODES + 255) / 256, 256, 0, stream>>>(deg);
    k_deg_acc<<<(N_EDGES + 255) / 256, 256, 0, stream>>>(ei, deg);
    k_dis<<<(N_NODES + 255) / 256, 256, 0, stream>>>(deg);

    // hlin = x @ W_gcn   [100000,256] @ [256,256]
    gemm_f32<<<dim3((N_NODES + 127) / 128, 2), 256, 0, stream>>>(x, Wg, hlin, N_NODES, 256, 256);

    // h = b_gcn + dis^2 * hlin
    k_hinit<<<(N_NODES * 64 + 255) / 256, 256, 0, stream>>>(hlin, deg, bg, h);

    // h[dst] += hlin[src] * dis[src]*dis[dst]
    k_scatter<<<N_EDGES / 4, 256, 0, stream>>>(hlin, ei, deg, h);

    // g = h @ W1   [100000,256] @ [256,128]   (into hlin buffer, hlin is dead)
    gemm_f32<<<dim3((N_NODES + 127) / 128, 1), 256, 0, stream>>>(h, W1, hlin, N_NODES, 128, 256);

    // fused per-edge MLP
    k_edge_mlp<<<N_LABEL / 4, 256, 0, stream>>>(hlin, eli, b1, W2, b2, W3, b3, out);
}

// Round 3
// 823.136 us; speedup vs baseline: 4.0788x; 4.0788x over previous
//
#include <hip/hip_runtime.h>

#define N_NODES 100000
#define N_EDGES 800000
#define N_LABEL 400000
// IN_CH = 256, OUT_CH = 256, H1 = 128, H2 = 32
// Key algebra: b_gcn cancels in h[dst]-h[src]; h@W1 = S_hat (x @ (W_gcn@W1)).
// So we only ever need p = S_hat(x@Wf) [100k,128], Wf = W_gcn@W1.

// ---------------- init counters ----------------
__global__ void k_zero2(int* __restrict__ a, int* __restrict__ b) {
    int i = blockIdx.x * 256 + threadIdx.x;
    if (i < N_NODES) { a[i] = 0; b[i] = 0; }
}

__global__ void k_count(const int* __restrict__ ei, int* __restrict__ cnt) {
    int e = blockIdx.x * 256 + threadIdx.x;
    if (e < N_EDGES) atomicAdd(&cnt[ei[N_EDGES + e]], 1);  // dst = ei[1][e]
}

__global__ void k_dis(const int* __restrict__ cnt, float* __restrict__ dis) {
    int i = blockIdx.x * 256 + threadIdx.x;
    if (i < N_NODES) dis[i] = rsqrtf((float)(cnt[i] + 1));  // +1 self loop
}

// ---------------- single-block exclusive scan over cnt -> rowptr ----------------
__global__ __launch_bounds__(1024) void k_scan(const int* __restrict__ cnt,
                                               int* __restrict__ rowptr) {
    __shared__ int sums[1024];
    const int t = threadIdx.x;
    const int CH = (N_NODES + 1023) / 1024;  // 98
    const int base = t * CH;
    int s = 0;
    for (int i = 0; i < CH; ++i) {
        int idx = base + i;
        if (idx < N_NODES) s += cnt[idx];
    }
    sums[t] = s;
    __syncthreads();
    for (int off = 1; off < 1024; off <<= 1) {
        int v = (t >= off) ? sums[t - off] : 0;
        __syncthreads();
        sums[t] += v;
        __syncthreads();
    }
    int run = (t == 0) ? 0 : sums[t - 1];
    for (int i = 0; i < CH; ++i) {
        int idx = base + i;
        if (idx < N_NODES) { rowptr[idx] = run; run += cnt[idx]; }
    }
    if (t == 1023) rowptr[N_NODES] = run;  // == N_EDGES
}

__global__ void k_fill(const int* __restrict__ ei, const int* __restrict__ rowptr,
                       int* __restrict__ cursor, int* __restrict__ csr) {
    int e = blockIdx.x * 256 + threadIdx.x;
    if (e >= N_EDGES) return;
    int src = ei[e];
    int dst = ei[N_EDGES + e];
    int pos = rowptr[dst] + atomicAdd(&cursor[dst], 1);
    csr[pos] = src;
}

// ---------------- fp32 tiled GEMM: C[M,N] = A[M,K] @ B[K,N], opt row-scale ----
// BM=BN=128, BK=16, 256 threads, 8x8 per thread. N % 128 == 0, K % 16 == 0.
__global__ __launch_bounds__(256) void gemm_f32(
    const float* __restrict__ A, const float* __restrict__ B,
    float* __restrict__ C, int M, int N, int K,
    const float* __restrict__ rowscale) {
    __shared__ float As[16][132];
    __shared__ float Bs[16][132];

    const int tid = threadIdx.x;
    const int tx = tid & 15, ty = tid >> 4;
    const int m0 = blockIdx.x * 128, n0 = blockIdx.y * 128;

    const int ar = tid >> 2;
    const int ac = (tid & 3) * 4;
    const int bk = tid >> 5;
    const int bc = (tid & 31) * 4;

    float acc[8][8] = {};

    for (int k0 = 0; k0 < K; k0 += 16) {
        #pragma unroll
        for (int hh = 0; hh < 2; ++hh) {
            int row = m0 + ar + hh * 64;
            float4 v = {0.f, 0.f, 0.f, 0.f};
            if (row < M) v = *(const float4*)&A[(size_t)row * K + k0 + ac];
            As[ac + 0][ar + hh * 64] = v.x;
            As[ac + 1][ar + hh * 64] = v.y;
            As[ac + 2][ar + hh * 64] = v.z;
            As[ac + 3][ar + hh * 64] = v.w;
        }
        #pragma unroll
        for (int hh = 0; hh < 2; ++hh) {
            int krow = k0 + bk + hh * 8;
            float4 v = *(const float4*)&B[(size_t)krow * N + n0 + bc];
            *(float4*)&Bs[bk + hh * 8][bc] = v;
        }
        __syncthreads();

        #pragma unroll
        for (int kk = 0; kk < 16; ++kk) {
            const float4 a0 = *(const float4*)&As[kk][ty * 8];
            const float4 a1 = *(const float4*)&As[kk][ty * 8 + 4];
            const float4 b0 = *(const float4*)&Bs[kk][tx * 8];
            const float4 b1 = *(const float4*)&Bs[kk][tx * 8 + 4];
            const float aa[8] = {a0.x, a0.y, a0.z, a0.w, a1.x, a1.y, a1.z, a1.w};
            const float bb[8] = {b0.x, b0.y, b0.z, b0.w, b1.x, b1.y, b1.z, b1.w};
            #pragma unroll
            for (int i = 0; i < 8; ++i)
                #pragma unroll
                for (int j = 0; j < 8; ++j)
                    acc[i][j] = fmaf(aa[i], bb[j], acc[i][j]);
        }
        __syncthreads();
    }

    #pragma unroll
    for (int i = 0; i < 8; ++i) {
        int row = m0 + ty * 8 + i;
        if (row < M) {
            float s = rowscale ? rowscale[row] : 1.0f;
            float4 c0 = {acc[i][0] * s, acc[i][1] * s, acc[i][2] * s, acc[i][3] * s};
            float4 c1 = {acc[i][4] * s, acc[i][5] * s, acc[i][6] * s, acc[i][7] * s};
            *(float4*)&C[(size_t)row * N + n0 + tx * 8] = c0;
            *(float4*)&C[(size_t)row * N + n0 + tx * 8 + 4] = c1;
        }
    }
}

// ---------------- CSR gather: p[i] = dis[i] * (qs[i] + sum qs[csr[j]]) --------
__global__ __launch_bounds__(256) void k_gather(
    const float* __restrict__ qs, const int* __restrict__ rowptr,
    const int* __restrict__ csr, const float* __restrict__ dis,
    float* __restrict__ p) {
    int node = blockIdx.x * 4 + (threadIdx.x >> 6);
    if (node >= N_NODES) return;
    int lane = threadIdx.x & 63;
    int beg = rowptr[node], end = rowptr[node + 1];
    float2 acc = *(const float2*)&qs[(size_t)node * 128 + lane * 2];
    for (int j = beg; j < end; ++j) {
        int src = csr[j];
        float2 v = *(const float2*)&qs[(size_t)src * 128 + lane * 2];
        acc.x += v.x;
        acc.y += v.y;
    }
    float d = dis[node];
    float2 r = {acc.x * d, acc.y * d};
    *(float2*)&p[(size_t)node * 128 + lane * 2] = r;
}

// ---------------- fused edge MLP ----------------
__global__ __launch_bounds__(256) void k_edge_mlp(
    const float* __restrict__ p, const int* __restrict__ eli,
    const float* __restrict__ b1, const float* __restrict__ W2,
    const float* __restrict__ b2, const float* __restrict__ W3,
    const float* __restrict__ b3, float* __restrict__ out) {
    __shared__ float sW2[128 * 32];
    __shared__ float st[4][128];

    const int tid = threadIdx.x;
    #pragma unroll
    for (int i = tid * 4; i < 4096; i += 1024)
        *(float4*)&sW2[i] = *(const float4*)&W2[i];

    const int wave = tid >> 6, lane = tid & 63;
    const int e = blockIdx.x * 4 + wave;
    const int src = eli[e];
    const int dst = eli[N_LABEL + e];

    float gd0 = p[(size_t)dst * 128 + lane];
    float gd1 = p[(size_t)dst * 128 + 64 + lane];
    float gs0 = p[(size_t)src * 128 + lane];
    float gs1 = p[(size_t)src * 128 + 64 + lane];
    float t0 = fmaxf(gd0 - gs0 + b1[lane], 0.f);
    float t1 = fmaxf(gd1 - gs1 + b1[64 + lane], 0.f);
    st[wave][lane] = t0;
    st[wave][64 + lane] = t1;
    __syncthreads();

    float r = 0.f;
    if (lane < 32) {
        float acc = b2[lane];
        #pragma unroll 4
        for (int k = 0; k < 128; ++k)
            acc = fmaf(st[wave][k], sW2[k * 32 + lane], acc);
        r = fmaxf(acc, 0.f) * W3[lane];
        #pragma unroll
        for (int m = 16; m; m >>= 1) r += __shfl_xor(r, m);
        if (lane == 0) out[e] = r + b3[0];
    }
}

// ---------------- launch ----------------
extern "C" void kernel_launch(void* const* d_in, const int* in_sizes, int n_in,
                              void* d_out, int out_size, void* d_ws, size_t ws_size,
                              hipStream_t stream) {
    const float* x   = (const float*)d_in[0];
    const int*   ei  = (const int*)d_in[1];
    const int*   eli = (const int*)d_in[2];
    const float* Wg  = (const float*)d_in[3];
    // d_in[4] = b_gcn : cancels in h[dst]-h[src], unused
    const float* W1  = (const float*)d_in[5];
    const float* b1  = (const float*)d_in[6];
    const float* W2  = (const float*)d_in[7];
    const float* b2  = (const float*)d_in[8];
    const float* W3  = (const float*)d_in[9];
    const float* b3  = (const float*)d_in[10];
    float* out = (float*)d_out;

    // ---- workspace layout (bytes), all regions disjoint & 16B-aligned ----
    // dis    [0,         524288)   400KB used
    // cnt    [524288,   1048576)
    // cursor [1048576,  1572864)
    // rowptr [1572864,  2097152)   needs 400004 B
    // csr    [2097152,  6291456)   needs 3.2MB, reserved 4MB
    // Wf     [6291456,  6422528)   128KB
    // qs     [8388608, 59588608)   51.2MB
    // p      [59588608, 110788608) 51.2MB
    char* ws = (char*)d_ws;
    float* dis    = (float*)(ws + 0);
    int*   cnt    = (int*)(ws + 524288);
    int*   cursor = (int*)(ws + 1048576);
    int*   rowptr = (int*)(ws + 1572864);
    int*   csr    = (int*)(ws + 2097152);
    float* Wf     = (float*)(ws + 6291456);
    float* qs     = (float*)(ws + 8388608);
    float* p      = (float*)(ws + 59588608);

    // CSR build + degree norm
    k_zero2<<<(N_NODES + 255) / 256, 256, 0, stream>>>(cnt, cursor);
    k_count<<<(N_EDGES + 255) / 256, 256, 0, stream>>>(ei, cnt);
    k_dis<<<(N_NODES + 255) / 256, 256, 0, stream>>>(cnt, dis);
    k_scan<<<1, 1024, 0, stream>>>(cnt, rowptr);
    k_fill<<<(N_EDGES + 255) / 256, 256, 0, stream>>>(ei, rowptr, cursor, csr);

    // Wf = W_gcn @ W1   [256,256]@[256,128]
    gemm_f32<<<dim3(2, 1), 256, 0, stream>>>(Wg, W1, Wf, 256, 128, 256, nullptr);

    // qs = (x @ Wf) * dis[row]   [100000,256]@[256,128]
    gemm_f32<<<dim3((N_NODES + 127) / 128, 1), 256, 0, stream>>>(
        x, Wf, qs, N_NODES, 128, 256, dis);

    // p[i] = dis[i] * (qs[i] + sum_{src->i} qs[src])
    k_gather<<<(N_NODES + 3) / 4, 256, 0, stream>>>(qs, rowptr, csr, dis, p);

    // fused per-edge MLP
    k_edge_mlp<<<N_LABEL / 4, 256, 0, stream>>>(p, eli, b1, W2, b2, W3, b3, out);
}

// Round 4
// 653.514 us; speedup vs baseline: 5.1375x; 1.2596x over previous
//
#include <hip/hip_runtime.h>

#define N_NODES 100000
#define N_EDGES 800000
#define N_LABEL 400000
// IN_CH = 256, OUT_CH = 256, H1 = 128, H2 = 32
// Key algebra: b_gcn cancels in h[dst]-h[src]; h@W1 = S_hat (x @ (W_gcn@W1)).
// So we only ever need p = S_hat(x@Wf) [100k,128], Wf = W_gcn@W1.

// ---------------- init counters ----------------
__global__ void k_zero2(int* __restrict__ a, int* __restrict__ b) {
    int i = blockIdx.x * 256 + threadIdx.x;
    if (i < N_NODES) { a[i] = 0; b[i] = 0; }
}

__global__ void k_count(const int* __restrict__ ei, int* __restrict__ cnt) {
    int e = blockIdx.x * 256 + threadIdx.x;
    if (e < N_EDGES) atomicAdd(&cnt[ei[N_EDGES + e]], 1);  // dst = ei[1][e]
}

__global__ void k_dis(const int* __restrict__ cnt, float* __restrict__ dis) {
    int i = blockIdx.x * 256 + threadIdx.x;
    if (i < N_NODES) dis[i] = rsqrtf((float)(cnt[i] + 1));  // +1 self loop
}

// ---------------- single-block exclusive scan over cnt -> rowptr ----------------
__global__ __launch_bounds__(1024) void k_scan(const int* __restrict__ cnt,
                                               int* __restrict__ rowptr) {
    __shared__ int sums[1024];
    const int t = threadIdx.x;
    const int CH = (N_NODES + 1023) / 1024;  // 98
    const int base = t * CH;
    int s = 0;
    for (int i = 0; i < CH; ++i) {
        int idx = base + i;
        if (idx < N_NODES) s += cnt[idx];
    }
    sums[t] = s;
    __syncthreads();
    for (int off = 1; off < 1024; off <<= 1) {
        int v = (t >= off) ? sums[t - off] : 0;
        __syncthreads();
        sums[t] += v;
        __syncthreads();
    }
    int run = (t == 0) ? 0 : sums[t - 1];
    for (int i = 0; i < CH; ++i) {
        int idx = base + i;
        if (idx < N_NODES) { rowptr[idx] = run; run += cnt[idx]; }
    }
    if (t == 1023) rowptr[N_NODES] = run;  // == N_EDGES
}

__global__ void k_fill(const int* __restrict__ ei, const int* __restrict__ rowptr,
                       int* __restrict__ cursor, int* __restrict__ csr) {
    int e = blockIdx.x * 256 + threadIdx.x;
    if (e >= N_EDGES) return;
    int src = ei[e];
    int dst = ei[N_EDGES + e];
    int pos = rowptr[dst] + atomicAdd(&cursor[dst], 1);
    csr[pos] = src;
}

// ---------------- fp32 tiled GEMM: C[M,N] = A[M,K] @ B[K,N], opt row-scale ----
__global__ __launch_bounds__(256) void gemm_f32(
    const float* __restrict__ A, const float* __restrict__ B,
    float* __restrict__ C, int M, int N, int K,
    const float* __restrict__ rowscale) {
    __shared__ float As[16][132];
    __shared__ float Bs[16][132];

    const int tid = threadIdx.x;
    const int tx = tid & 15, ty = tid >> 4;
    const int m0 = blockIdx.x * 128, n0 = blockIdx.y * 128;

    const int ar = tid >> 2;
    const int ac = (tid & 3) * 4;
    const int bk = tid >> 5;
    const int bc = (tid & 31) * 4;

    float acc[8][8] = {};

    for (int k0 = 0; k0 < K; k0 += 16) {
        #pragma unroll
        for (int hh = 0; hh < 2; ++hh) {
            int row = m0 + ar + hh * 64;
            float4 v = {0.f, 0.f, 0.f, 0.f};
            if (row < M) v = *(const float4*)&A[(size_t)row * K + k0 + ac];
            As[ac + 0][ar + hh * 64] = v.x;
            As[ac + 1][ar + hh * 64] = v.y;
            As[ac + 2][ar + hh * 64] = v.z;
            As[ac + 3][ar + hh * 64] = v.w;
        }
        #pragma unroll
        for (int hh = 0; hh < 2; ++hh) {
            int krow = k0 + bk + hh * 8;
            float4 v = *(const float4*)&B[(size_t)krow * N + n0 + bc];
            *(float4*)&Bs[bk + hh * 8][bc] = v;
        }
        __syncthreads();

        #pragma unroll
        for (int kk = 0; kk < 16; ++kk) {
            const float4 a0 = *(const float4*)&As[kk][ty * 8];
            const float4 a1 = *(const float4*)&As[kk][ty * 8 + 4];
            const float4 b0 = *(const float4*)&Bs[kk][tx * 8];
            const float4 b1 = *(const float4*)&Bs[kk][tx * 8 + 4];
            const float aa[8] = {a0.x, a0.y, a0.z, a0.w, a1.x, a1.y, a1.z, a1.w};
            const float bb[8] = {b0.x, b0.y, b0.z, b0.w, b1.x, b1.y, b1.z, b1.w};
            #pragma unroll
            for (int i = 0; i < 8; ++i)
                #pragma unroll
                for (int j = 0; j < 8; ++j)
                    acc[i][j] = fmaf(aa[i], bb[j], acc[i][j]);
        }
        __syncthreads();
    }

    #pragma unroll
    for (int i = 0; i < 8; ++i) {
        int row = m0 + ty * 8 + i;
        if (row < M) {
            float s = rowscale ? rowscale[row] : 1.0f;
            float4 c0 = {acc[i][0] * s, acc[i][1] * s, acc[i][2] * s, acc[i][3] * s};
            float4 c1 = {acc[i][4] * s, acc[i][5] * s, acc[i][6] * s, acc[i][7] * s};
            *(float4*)&C[(size_t)row * N + n0 + tx * 8] = c0;
            *(float4*)&C[(size_t)row * N + n0 + tx * 8 + 4] = c1;
        }
    }
}

// ---------------- CSR gather: p[i] = dis[i] * (qs[i] + sum qs[csr[j]]) --------
__global__ __launch_bounds__(256) void k_gather(
    const float* __restrict__ qs, const int* __restrict__ rowptr,
    const int* __restrict__ csr, const float* __restrict__ dis,
    float* __restrict__ p) {
    int node = blockIdx.x * 4 + (threadIdx.x >> 6);
    if (node >= N_NODES) return;
    int lane = threadIdx.x & 63;
    int beg = rowptr[node], end = rowptr[node + 1];
    float2 acc = *(const float2*)&qs[(size_t)node * 128 + lane * 2];
    for (int j = beg; j < end; ++j) {
        int src = csr[j];
        float2 v = *(const float2*)&qs[(size_t)src * 128 + lane * 2];
        acc.x += v.x;
        acc.y += v.y;
    }
    float d = dis[node];
    float2 r = {acc.x * d, acc.y * d};
    *(float2*)&p[(size_t)node * 128 + lane * 2] = r;
}

// ---------------- fused edge MLP (v2: W2 in regs, all-64-lane layer 2) --------
// thread (o = lane&31, kh = lane>>5) holds W2[kh*64 + i][o], i<64, in VGPRs.
// Per edge: layer1 in regs -> t row in per-wave LDS -> broadcast ds_read_b128
// + 64 FMA -> shfl_xor(32) k-half merge -> relu,*W3 -> 5-shfl reduce -> store.
// 16 edges per wave, 4 waves per block, grid = 400000/64 = 6250 blocks.
__global__ __launch_bounds__(256, 4) void k_edge_mlp(
    const float* __restrict__ p, const int* __restrict__ eli,
    const float* __restrict__ b1, const float* __restrict__ W2,
    const float* __restrict__ b2, const float* __restrict__ W3,
    const float* __restrict__ b3, float* __restrict__ out) {
    __shared__ float st[4][128];

    const int tid = threadIdx.x;
    const int wave = tid >> 6, lane = tid & 63;
    const int o = lane & 31, kh = lane >> 5;

    // W2 column-half in registers (reused for all 16 edges)
    float w2r[64];
    #pragma unroll
    for (int i = 0; i < 64; ++i)
        w2r[i] = W2[(kh * 64 + i) * 32 + o];

    const float b2r = b2[o];
    const float w3r = W3[o];
    const float b3r = b3[0];
    const float2 bb = *(const float2*)&b1[lane * 2];

    const int e0 = (blockIdx.x * 4 + wave) * 16;

    #pragma unroll 2
    for (int t = 0; t < 16; ++t) {
        const int e = e0 + t;
        const int src = eli[e];
        const int dst = eli[N_LABEL + e];
        const float2 pd = *(const float2*)&p[(size_t)dst * 128 + lane * 2];
        const float2 ps = *(const float2*)&p[(size_t)src * 128 + lane * 2];
        const float t0 = fmaxf(pd.x - ps.x + bb.x, 0.f);
        const float t1 = fmaxf(pd.y - ps.y + bb.y, 0.f);
        *(float2*)&st[wave][lane * 2] = make_float2(t0, t1);
        // same-wave LDS RAW: compiler inserts lgkmcnt wait, no barrier needed
        float acc = 0.f;
        #pragma unroll
        for (int i = 0; i < 64; i += 4) {
            const float4 tv = *(const float4*)&st[wave][kh * 64 + i];
            acc = fmaf(tv.x, w2r[i + 0], acc);
            acc = fmaf(tv.y, w2r[i + 1], acc);
            acc = fmaf(tv.z, w2r[i + 2], acc);
            acc = fmaf(tv.w, w2r[i + 3], acc);
        }
        acc += __shfl_xor(acc, 32);               // merge k-halves
        float u = fmaxf(acc + b2r, 0.f) * w3r;    // layer3 partial per o
        #pragma unroll
        for (int m = 16; m; m >>= 1) u += __shfl_xor(u, m);
        if (lane == 0) out[e] = u + b3r;
    }
}

// ---------------- launch ----------------
extern "C" void kernel_launch(void* const* d_in, const int* in_sizes, int n_in,
                              void* d_out, int out_size, void* d_ws, size_t ws_size,
                              hipStream_t stream) {
    const float* x   = (const float*)d_in[0];
    const int*   ei  = (const int*)d_in[1];
    const int*   eli = (const int*)d_in[2];
    const float* Wg  = (const float*)d_in[3];
    // d_in[4] = b_gcn : cancels in h[dst]-h[src], unused
    const float* W1  = (const float*)d_in[5];
    const float* b1  = (const float*)d_in[6];
    const float* W2  = (const float*)d_in[7];
    const float* b2  = (const float*)d_in[8];
    const float* W3  = (const float*)d_in[9];
    const float* b3  = (const float*)d_in[10];
    float* out = (float*)d_out;

    // ---- workspace layout (bytes), all regions disjoint & 16B-aligned ----
    char* ws = (char*)d_ws;
    float* dis    = (float*)(ws + 0);           // 400 KB
    int*   cnt    = (int*)(ws + 524288);        // 400 KB
    int*   cursor = (int*)(ws + 1048576);       // 400 KB
    int*   rowptr = (int*)(ws + 1572864);       // 400 KB + 4
    int*   csr    = (int*)(ws + 2097152);       // 3.2 MB (4 MB reserved)
    float* Wf     = (float*)(ws + 6291456);     // 128 KB
    float* qs     = (float*)(ws + 8388608);     // 51.2 MB
    float* p      = (float*)(ws + 59588608);    // 51.2 MB

    // CSR build + degree norm
    k_zero2<<<(N_NODES + 255) / 256, 256, 0, stream>>>(cnt, cursor);
    k_count<<<(N_EDGES + 255) / 256, 256, 0, stream>>>(ei, cnt);
    k_dis<<<(N_NODES + 255) / 256, 256, 0, stream>>>(cnt, dis);
    k_scan<<<1, 1024, 0, stream>>>(cnt, rowptr);
    k_fill<<<(N_EDGES + 255) / 256, 256, 0, stream>>>(ei, rowptr, cursor, csr);

    // Wf = W_gcn @ W1   [256,256]@[256,128]
    gemm_f32<<<dim3(2, 1), 256, 0, stream>>>(Wg, W1, Wf, 256, 128, 256, nullptr);

    // qs = (x @ Wf) * dis[row]   [100000,256]@[256,128]
    gemm_f32<<<dim3((N_NODES + 127) / 128, 1), 256, 0, stream>>>(
        x, Wf, qs, N_NODES, 128, 256, dis);

    // p[i] = dis[i] * (qs[i] + sum_{src->i} qs[src])
    k_gather<<<(N_NODES + 3) / 4, 256, 0, stream>>>(qs, rowptr, csr, dis, p);

    // fused per-edge MLP: 16 edges/wave, 4 waves/block
    k_edge_mlp<<<N_LABEL / 64, 256, 0, stream>>>(p, eli, b1, W2, b2, W3, b3, out);
}

// Round 5
// 481.153 us; speedup vs baseline: 6.9779x; 1.3582x over previous
//
#include <hip/hip_runtime.h>

#define N_NODES 100000
#define N_EDGES 800000
#define N_LABEL 400000
// IN_CH = 256, OUT_CH = 256, H1 = 128, H2 = 32
// Key algebra: b_gcn cancels in h[dst]-h[src]; h@W1 = S_hat (x @ (W_gcn@W1)).
// So we only ever need p = S_hat(x@Wf) [100k,128], Wf = W_gcn@W1.

// ---------------- init counters ----------------
__global__ void k_zero2(int* __restrict__ a, int* __restrict__ b) {
    int i = blockIdx.x * 256 + threadIdx.x;
    if (i < N_NODES) { a[i] = 0; b[i] = 0; }
}

__global__ void k_count(const int* __restrict__ ei, int* __restrict__ cnt) {
    int e = blockIdx.x * 256 + threadIdx.x;
    if (e < N_EDGES) atomicAdd(&cnt[ei[N_EDGES + e]], 1);  // dst = ei[1][e]
}

__global__ void k_dis(const int* __restrict__ cnt, float* __restrict__ dis) {
    int i = blockIdx.x * 256 + threadIdx.x;
    if (i < N_NODES) dis[i] = rsqrtf((float)(cnt[i] + 1));  // +1 self loop
}

// ---------------- hierarchical exclusive scan: cnt -> rowptr ----------------
// L1: per-block (1024-chunk) sums
__global__ __launch_bounds__(1024) void k_bsum(const int* __restrict__ cnt,
                                               int* __restrict__ bsum) {
    __shared__ int red[1024];
    int t = threadIdx.x;
    int i = blockIdx.x * 1024 + t;
    red[t] = (i < N_NODES) ? cnt[i] : 0;
    __syncthreads();
    #pragma unroll
    for (int off = 512; off; off >>= 1) {
        if (t < off) red[t] += red[t + off];
        __syncthreads();
    }
    if (t == 0) bsum[blockIdx.x] = red[0];
}

// L2: exclusive scan of nb (<=128) block sums, in place
__global__ void k_bscan(int* __restrict__ bsum, int nb) {
    __shared__ int s[128];
    int t = threadIdx.x;
    s[t] = (t < nb) ? bsum[t] : 0;
    __syncthreads();
    #pragma unroll
    for (int off = 1; off < 128; off <<= 1) {
        int v = (t >= off) ? s[t - off] : 0;
        __syncthreads();
        s[t] += v;
        __syncthreads();
    }
    if (t < nb) bsum[t] = t ? s[t - 1] : 0;
}

// L3: intra-block scan + block offset -> rowptr (exclusive), plus rowptr[N]
__global__ __launch_bounds__(1024) void k_rowptr(const int* __restrict__ cnt,
                                                 const int* __restrict__ bsum,
                                                 int* __restrict__ rowptr) {
    __shared__ int s[1024];
    int t = threadIdx.x;
    int i = blockIdx.x * 1024 + t;
    int v = (i < N_NODES) ? cnt[i] : 0;
    s[t] = v;
    __syncthreads();
    #pragma unroll
    for (int off = 1; off < 1024; off <<= 1) {
        int u = (t >= off) ? s[t - off] : 0;
        __syncthreads();
        s[t] += u;
        __syncthreads();
    }
    int excl = s[t] - v + bsum[blockIdx.x];
    if (i < N_NODES) rowptr[i] = excl;
    if (i == N_NODES - 1) rowptr[N_NODES] = excl + v;  // == N_EDGES
}

__global__ void k_fill(const int* __restrict__ ei, const int* __restrict__ rowptr,
                       int* __restrict__ cursor, int* __restrict__ csr) {
    int e = blockIdx.x * 256 + threadIdx.x;
    if (e >= N_EDGES) return;
    int src = ei[e];
    int dst = ei[N_EDGES + e];
    int pos = rowptr[dst] + atomicAdd(&cursor[dst], 1);
    csr[pos] = src;
}

// ---------------- fp32 tiled GEMM: C[M,N] = A[M,K] @ B[K,N], opt row-scale ----
__global__ __launch_bounds__(256) void gemm_f32(
    const float* __restrict__ A, const float* __restrict__ B,
    float* __restrict__ C, int M, int N, int K,
    const float* __restrict__ rowscale) {
    __shared__ float As[16][132];
    __shared__ float Bs[16][132];

    const int tid = threadIdx.x;
    const int tx = tid & 15, ty = tid >> 4;
    const int m0 = blockIdx.x * 128, n0 = blockIdx.y * 128;

    const int ar = tid >> 2;
    const int ac = (tid & 3) * 4;
    const int bk = tid >> 5;
    const int bc = (tid & 31) * 4;

    float acc[8][8] = {};

    for (int k0 = 0; k0 < K; k0 += 16) {
        #pragma unroll
        for (int hh = 0; hh < 2; ++hh) {
            int row = m0 + ar + hh * 64;
            float4 v = {0.f, 0.f, 0.f, 0.f};
            if (row < M) v = *(const float4*)&A[(size_t)row * K + k0 + ac];
            As[ac + 0][ar + hh * 64] = v.x;
            As[ac + 1][ar + hh * 64] = v.y;
            As[ac + 2][ar + hh * 64] = v.z;
            As[ac + 3][ar + hh * 64] = v.w;
        }
        #pragma unroll
        for (int hh = 0; hh < 2; ++hh) {
            int krow = k0 + bk + hh * 8;
            float4 v = *(const float4*)&B[(size_t)krow * N + n0 + bc];
            *(float4*)&Bs[bk + hh * 8][bc] = v;
        }
        __syncthreads();

        #pragma unroll
        for (int kk = 0; kk < 16; ++kk) {
            const float4 a0 = *(const float4*)&As[kk][ty * 8];
            const float4 a1 = *(const float4*)&As[kk][ty * 8 + 4];
            const float4 b0 = *(const float4*)&Bs[kk][tx * 8];
            const float4 b1 = *(const float4*)&Bs[kk][tx * 8 + 4];
            const float aa[8] = {a0.x, a0.y, a0.z, a0.w, a1.x, a1.y, a1.z, a1.w};
            const float bb[8] = {b0.x, b0.y, b0.z, b0.w, b1.x, b1.y, b1.z, b1.w};
            #pragma unroll
            for (int i = 0; i < 8; ++i)
                #pragma unroll
                for (int j = 0; j < 8; ++j)
                    acc[i][j] = fmaf(aa[i], bb[j], acc[i][j]);
        }
        __syncthreads();
    }

    #pragma unroll
    for (int i = 0; i < 8; ++i) {
        int row = m0 + ty * 8 + i;
        if (row < M) {
            float s = rowscale ? rowscale[row] : 1.0f;
            float4 c0 = {acc[i][0] * s, acc[i][1] * s, acc[i][2] * s, acc[i][3] * s};
            float4 c1 = {acc[i][4] * s, acc[i][5] * s, acc[i][6] * s, acc[i][7] * s};
            *(float4*)&C[(size_t)row * N + n0 + tx * 8] = c0;
            *(float4*)&C[(size_t)row * N + n0 + tx * 8 + 4] = c1;
        }
    }
}

// ---------------- CSR gather: p[i] = dis[i] * (qs[i] + sum qs[csr[j]]) --------
__global__ __launch_bounds__(256) void k_gather(
    const float* __restrict__ qs, const int* __restrict__ rowptr,
    const int* __restrict__ csr, const float* __restrict__ dis,
    float* __restrict__ p) {
    int node = blockIdx.x * 4 + (threadIdx.x >> 6);
    if (node >= N_NODES) return;
    int lane = threadIdx.x & 63;
    int beg = rowptr[node], end = rowptr[node + 1];
    float2 acc = *(const float2*)&qs[(size_t)node * 128 + lane * 2];
    for (int j = beg; j < end; ++j) {
        int src = csr[j];
        float2 v = *(const float2*)&qs[(size_t)src * 128 + lane * 2];
        acc.x += v.x;
        acc.y += v.y;
    }
    float d = dis[node];
    float2 r = {acc.x * d, acc.y * d};
    *(float2*)&p[(size_t)node * 128 + lane * 2] = r;
}

// ---------------- fused edge MLP (v2: W2 in regs, all-64-lane layer 2) --------
__global__ __launch_bounds__(256, 4) void k_edge_mlp(
    const float* __restrict__ p, const int* __restrict__ eli,
    const float* __restrict__ b1, const float* __restrict__ W2,
    const float* __restrict__ b2, const float* __restrict__ W3,
    const float* __restrict__ b3, float* __restrict__ out) {
    __shared__ float st[4][128];

    const int tid = threadIdx.x;
    const int wave = tid >> 6, lane = tid & 63;
    const int o = lane & 31, kh = lane >> 5;

    // W2 column-half in registers (reused for all 16 edges)
    float w2r[64];
    #pragma unroll
    for (int i = 0; i < 64; ++i)
        w2r[i] = W2[(kh * 64 + i) * 32 + o];

    const float b2r = b2[o];
    const float w3r = W3[o];
    const float b3r = b3[0];
    const float2 bb = *(const float2*)&b1[lane * 2];

    const int e0 = (blockIdx.x * 4 + wave) * 16;

    #pragma unroll 2
    for (int t = 0; t < 16; ++t) {
        const int e = e0 + t;
        const int src = eli[e];
        const int dst = eli[N_LABEL + e];
        const float2 pd = *(const float2*)&p[(size_t)dst * 128 + lane * 2];
        const float2 ps = *(const float2*)&p[(size_t)src * 128 + lane * 2];
        const float t0 = fmaxf(pd.x - ps.x + bb.x, 0.f);
        const float t1 = fmaxf(pd.y - ps.y + bb.y, 0.f);
        *(float2*)&st[wave][lane * 2] = make_float2(t0, t1);
        float acc = 0.f;
        #pragma unroll
        for (int i = 0; i < 64; i += 4) {
            const float4 tv = *(const float4*)&st[wave][kh * 64 + i];
            acc = fmaf(tv.x, w2r[i + 0], acc);
            acc = fmaf(tv.y, w2r[i + 1], acc);
            acc = fmaf(tv.z, w2r[i + 2], acc);
            acc = fmaf(tv.w, w2r[i + 3], acc);
        }
        acc += __shfl_xor(acc, 32);               // merge k-halves
        float u = fmaxf(acc + b2r, 0.f) * w3r;    // layer3 partial per o
        #pragma unroll
        for (int m = 16; m; m >>= 1) u += __shfl_xor(u, m);
        if (lane == 0) out[e] = u + b3r;
    }
}

// ---------------- launch ----------------
extern "C" void kernel_launch(void* const* d_in, const int* in_sizes, int n_in,
                              void* d_out, int out_size, void* d_ws, size_t ws_size,
                              hipStream_t stream) {
    const float* x   = (const float*)d_in[0];
    const int*   ei  = (const int*)d_in[1];
    const int*   eli = (const int*)d_in[2];
    const float* Wg  = (const float*)d_in[3];
    // d_in[4] = b_gcn : cancels in h[dst]-h[src], unused
    const float* W1  = (const float*)d_in[5];
    const float* b1  = (const float*)d_in[6];
    const float* W2  = (const float*)d_in[7];
    const float* b2  = (const float*)d_in[8];
    const float* W3  = (const float*)d_in[9];
    const float* b3  = (const float*)d_in[10];
    float* out = (float*)d_out;

    // ---- workspace layout (bytes), all regions disjoint & 16B-aligned ----
    char* ws = (char*)d_ws;
    float* dis    = (float*)(ws + 0);           // 400 KB
    int*   cnt    = (int*)(ws + 524288);        // 400 KB
    int*   cursor = (int*)(ws + 1048576);       // 400 KB
    int*   rowptr = (int*)(ws + 1572864);       // 400 KB + 4
    int*   bsum   = (int*)(ws + 2000000);       // 512 B (98 ints)
    int*   csr    = (int*)(ws + 2097152);       // 3.2 MB (4 MB reserved)
    float* Wf     = (float*)(ws + 6291456);     // 128 KB
    float* qs     = (float*)(ws + 8388608);     // 51.2 MB
    float* p      = (float*)(ws + 59588608);    // 51.2 MB

    const int NB = (N_NODES + 1023) / 1024;     // 98

    // CSR build + degree norm
    k_zero2<<<(N_NODES + 255) / 256, 256, 0, stream>>>(cnt, cursor);
    k_count<<<(N_EDGES + 255) / 256, 256, 0, stream>>>(ei, cnt);
    k_dis<<<(N_NODES + 255) / 256, 256, 0, stream>>>(cnt, dis);
    k_bsum<<<NB, 1024, 0, stream>>>(cnt, bsum);
    k_bscan<<<1, 128, 0, stream>>>(bsum, NB);
    k_rowptr<<<NB, 1024, 0, stream>>>(cnt, bsum, rowptr);
    k_fill<<<(N_EDGES + 255) / 256, 256, 0, stream>>>(ei, rowptr, cursor, csr);

    // Wf = W_gcn @ W1   [256,256]@[256,128]
    gemm_f32<<<dim3(2, 1), 256, 0, stream>>>(Wg, W1, Wf, 256, 128, 256, nullptr);

    // qs = (x @ Wf) * dis[row]   [100000,256]@[256,128]
    gemm_f32<<<dim3((N_NODES + 127) / 128, 1), 256, 0, stream>>>(
        x, Wf, qs, N_NODES, 128, 256, dis);

    // p[i] = dis[i] * (qs[i] + sum_{src->i} qs[src])
    k_gather<<<(N_NODES + 3) / 4, 256, 0, stream>>>(qs, rowptr, csr, dis, p);

    // fused per-edge MLP: 16 edges/wave, 4 waves/block
    k_edge_mlp<<<N_LABEL / 64, 256, 0, stream>>>(p, eli, b1, W2, b2, W3, b3, out);
}